// Round 2
// baseline (5897.796 us; speedup 1.0000x reference)
//
#include <hip/hip_runtime.h>
#include <hip/hip_bf16.h>
#include <stdint.h>

// ---------------------------------------------------------------------------
// VGG attention-erase pipeline, bf16 MFMA implicit-im2col convs.
// Activations channels-last, spatially padded: [b][30][32][C] bf16.
// Weights in MFMA-coalesced layout [p][O/16][C/32][lane64][8] bf16 so each
// B-fragment load is one contiguous 1KB wave fetch; p+1 weights prefetched
// into VGPRs behind p's MFMAs. Activations double-buffered in LDS (one
// barrier per K-chunk), staged via global_load_lds(16B, NT) with an XOR
// swizzle (kq ^ ((rc>>1)&3)) giving 2-way-max bank aliasing (free).
// ---------------------------------------------------------------------------

typedef __attribute__((ext_vector_type(8))) short short8;
typedef __attribute__((ext_vector_type(4))) float floatx4;

__device__ __forceinline__ unsigned short f2bf(float f) {
  union { float f; uint32_t u; } cv; cv.f = f;
  uint32_t u = cv.u;
  u += 0x7fffu + ((u >> 16) & 1u);   // round-to-nearest-even
  return (unsigned short)(u >> 16);
}

// --- weight prep: w[O][C][3][3] f32 -> wt[p][O/16][C/32][lane][8] bf16 ------
__global__ void wprep3(const float* __restrict__ w, unsigned short* __restrict__ wt,
                       int O, int C) {
  int i = blockIdx.x * 256 + threadIdx.x;
  if (i >= 9 * O * C) return;
  int j = i & 7;
  int lane = (i >> 3) & 63;
  int kt = (i >> 9) % (C >> 5);
  int rest = (i >> 9) / (C >> 5);
  int ot = rest % (O >> 4);
  int p = rest / (O >> 4);
  int ln = lane & 15, kq = lane >> 4;
  int o = ot * 16 + ln;
  int c = kt * 32 + kq * 8 + j;
  wt[i] = f2bf(w[(size_t)(o * C + c) * 9 + p]);
}

// --- weight prep 1x1: w[O][C] f32 -> wt[OP/16][C/32][lane][8] (zero pad) ----
__global__ void wprep1(const float* __restrict__ w, unsigned short* __restrict__ wt,
                       int O, int OP, int C) {
  int i = blockIdx.x * 256 + threadIdx.x;
  if (i >= OP * C) return;
  int j = i & 7;
  int lane = (i >> 3) & 63;
  int kt = (i >> 9) % (C >> 5);
  int ot = (i >> 9) / (C >> 5);
  int ln = lane & 15, kq = lane >> 4;
  int o = ot * 16 + ln;
  int c = kt * 32 + kq * 8 + j;
  wt[i] = (o < O) ? f2bf(w[(size_t)o * C + c]) : (unsigned short)0;
}

// ------ avgpool 3x3/9 (count_include_pad) + transpose to ch-last padded -----
// x: [32][512][28][28] f32  ->  fp: [32][30][32][512] bf16 (borders zero)
__global__ void avgpool_k(const float* __restrict__ x, unsigned short* __restrict__ fp) {
  const int C = 512;
  int b = blockIdx.x, r = blockIdx.y, cg = blockIdx.z;  // r: padded row 0..29
  int t = threadIdx.x;
  __shared__ float xs[3 * 128 * 29];
  if (r == 0 || r == 29) {
    for (int i = t; i < 32 * 128; i += 256) {
      int c = i & 127, col = i >> 7;
      fp[((size_t)(b * 30 + r) * 32 + col) * C + cg * 128 + c] = 0;
    }
    return;
  }
  for (int i = t; i < 3 * 128 * 28; i += 256) {
    int dy = i / 3584;
    int rem = i - dy * 3584;
    int c = rem / 28, fx = rem - c * 28;
    int fy = r - 2 + dy;
    float v = (fy >= 0 && fy < 28)
                  ? x[((size_t)(b * 512 + cg * 128 + c) * 28 + fy) * 28 + fx]
                  : 0.f;
    xs[(dy * 128 + c) * 29 + fx] = v;
  }
  __syncthreads();
  for (int i = t; i < 32 * 128; i += 256) {
    int c = i & 127, col = i >> 7;
    float v = 0.f;
    if (col >= 1 && col <= 28) {
      int fx0 = col - 1;
#pragma unroll
      for (int dy = 0; dy < 3; ++dy)
#pragma unroll
        for (int dx = 0; dx < 3; ++dx) {
          int fx = fx0 - 1 + dx;
          if (fx >= 0 && fx < 28) v += xs[(dy * 128 + c) * 29 + fx];
        }
      v *= (1.f / 9.f);
    }
    fp[((size_t)(b * 30 + r) * 32 + col) * C + cg * 128 + c] = f2bf(v);
  }
}

// ---------- zero the padded borders of h1p/h2p (ws is poisoned per call) ----
__global__ void zero_borders(unsigned short* __restrict__ h1,
                             unsigned short* __restrict__ h2, int Mch) {
  int i = blockIdx.x * 256 + threadIdx.x;
  int vch = Mch >> 3;
  int perbuf = 32 * 176 * vch;
  if (i >= 2 * perbuf) return;
  unsigned short* h = (i < perbuf) ? h1 : h2;
  int j = (i < perbuf) ? i : i - perbuf;
  int cv = j % vch;
  int rr = j / vch;
  int bidx = rr / 176, e = rr - bidx * 176;
  int row, col;
  if (e < 32)      { row = 0;  col = e; }
  else if (e < 64) { row = 29; col = e - 32; }
  else {
    int q = e - 64;
    row = 1 + (q >> 2);
    int k = q & 3;
    col = (k == 0) ? 0 : 28 + k;
  }
  size_t addr = ((size_t)(bidx * 30 + row) * 32 + col) * Mch + cv * 8;
  *(uint4*)&h[addr] = (uint4){0u, 0u, 0u, 0u};
}

// ------------------------------- the conv GEMM ------------------------------
// fin: [B][30][32][C] bf16, wt: [P][M/16][C/32][64][8] bf16, bias: [OB] f32
// PADOUT=1: out bf16 [B][30][32][M] (interior only). PADOUT=0: out f32 [B][784][M].
template <int P, int RELU, int PADOUT>
__global__ __launch_bounds__(256, 2)
void conv_mfma(const unsigned short* __restrict__ fin,
               const unsigned short* __restrict__ wt,
               const float* __restrict__ bias,
               void* __restrict__ outp, int C, int M, int OB) {
  const int tid = threadIdx.x;
  const int lane = tid & 63;
  const int wave = tid >> 6;
  const int hB = wave & 1;      // batch half
  const int wo = wave >> 1;     // outch half
  const int ln = lane & 15;
  const int kq = lane >> 4;

  const int o0 = blockIdx.x * 128 + wo * 64;
  const int yo0 = blockIdx.y * 4;
  const int b0 = blockIdx.z * 2;
  const int bb = b0 + hB;

  __shared__ unsigned short ldsB[2 * 1536 * 8];  // 49152 B, double-buffered

  int baserc[7];
#pragma unroll
  for (int mi = 0; mi < 7; ++mi) {
    int n = mi * 16 + ln;
    int y = n / 28, x = n - y * 28;
    baserc[mi] = y * 32 + x;
  }

  floatx4 acc[7][4];
#pragma unroll
  for (int mi = 0; mi < 7; ++mi)
#pragma unroll
    for (int ni = 0; ni < 4; ++ni)
      acc[mi][ni] = (floatx4){0.f, 0.f, 0.f, 0.f};

  const size_t fin_b0 = (size_t)(b0 * 30 + yo0) * 32 * C;
  const size_t fin_b1 = (size_t)((b0 + 1) * 30 + yo0) * 32 * C;

  const int NC = C >> 5;
  const size_t wstep_n = (size_t)NC * 512;            // elements per o-tile
  const size_t wstep_p = (size_t)(M >> 4) * wstep_n;  // elements per p
  const unsigned short* wbase = wt + (size_t)(o0 >> 4) * wstep_n + lane * 8;

  auto stage = [&](int ckidx, int buf) {
    int ckoff = ckidx * 32;
#pragma unroll
    for (int it = 0; it < 6; ++it) {
      int wb = (it >= 3) ? 1 : 0;
      int u = (it - wb * 3) * 256 + tid;
      int rc = u >> 2;
      int cg = (u & 3) ^ ((rc >> 1) & 3);
      size_t goff = (wb ? fin_b1 : fin_b0) + (size_t)rc * C + ckoff + cg * 8;
      unsigned short* lp =
          &ldsB[(size_t)(buf * 1536 + wb * 768 + (it - wb * 3) * 256 + wave * 64) * 8];
      __builtin_amdgcn_global_load_lds((const uint32_t*)(fin + goff), (uint32_t*)lp,
                                       16, 0, 2 /*NT: don't evict weights from L2*/);
    }
  };

  stage(0, 0);
  for (int ck = 0; ck < NC; ++ck) {
    __syncthreads();                   // drains stage(ck) (in flight one full chunk)
    if (ck + 1 < NC) stage(ck + 1, (ck + 1) & 1);
    const unsigned short* ldsH = &ldsB[(size_t)((ck & 1) * 1536 + hB * 768) * 8];
    const unsigned short* wck = wbase + (size_t)ck * 512;

    short8 wfA[4], wfB[4];
#pragma unroll
    for (int ni = 0; ni < 4; ++ni)
      wfA[ni] = *(const short8*)(const void*)(wck + ni * wstep_n);

#pragma unroll
    for (int p = 0; p < P; ++p) {
      short8* wf  = (p & 1) ? wfB : wfA;
      short8* wfn = (p & 1) ? wfA : wfB;
      if (p + 1 < P) {
#pragma unroll
        for (int ni = 0; ni < 4; ++ni)
          wfn[ni] = *(const short8*)(const void*)(wck + (size_t)(p + 1) * wstep_p +
                                                  ni * wstep_n);
      }
      int dy, dx;
      if (P == 1) { dy = 1; dx = 1; } else { dy = p / 3; dx = p - dy * 3; }
      short8 af[7];
#pragma unroll
      for (int mi = 0; mi < 7; ++mi) {
        int rc = baserc[mi] + dy * 32 + dx;
        int u = (rc << 2) + (kq ^ ((rc >> 1) & 3));
        af[mi] = *(const short8*)(const void*)&ldsH[(unsigned)u * 8];
      }
#pragma unroll
      for (int mi = 0; mi < 7; ++mi)
#pragma unroll
        for (int ni = 0; ni < 4; ++ni)
          acc[mi][ni] = __builtin_amdgcn_mfma_f32_16x16x32_bf16(af[mi], wf[ni],
                                                                acc[mi][ni], 0, 0, 0);
    }
  }

  // epilogue: D[row=spatial=(kq*4+j within 16-tile)][col=outch=ln]
  float bia[4];
#pragma unroll
  for (int ni = 0; ni < 4; ++ni) {
    int o = o0 + ni * 16 + ln;
    bia[ni] = (o < OB) ? bias[o] : 0.f;
  }
#pragma unroll
  for (int mi = 0; mi < 7; ++mi) {
#pragma unroll
    for (int j = 0; j < 4; ++j) {
      int n = mi * 16 + kq * 4 + j;
      int y = n / 28, x = n - y * 28;
#pragma unroll
      for (int ni = 0; ni < 4; ++ni) {
        int o = o0 + ni * 16 + ln;
        float v = acc[mi][ni][j] + bia[ni];
        if (RELU) v = fmaxf(v, 0.f);
        if (PADOUT) {
          size_t addr = ((size_t)(bb * 30 + yo0 + y + 1) * 32 + (x + 1)) * M + o;
          __builtin_nontemporal_store(f2bf(v), (unsigned short*)outp + addr);
        } else {
          size_t addr = ((size_t)bb * 784 + (yo0 + y) * 28 + x) * M + o;
          __builtin_nontemporal_store(v, (float*)outp + addr);
        }
      }
    }
  }
}

// ------------- logits (+ optional attention/mask), one block per batch ------
template <int DO_ATTEN>
__global__ void logits_atten(const float* __restrict__ ob, const int* __restrict__ label,
                             float* __restrict__ outp, float* __restrict__ mask) {
  int b = blockIdx.x, t = threadIdx.x;
  const float* base = ob + (size_t)b * 784 * 256;
  float s = 0.f;
#pragma unroll 16
  for (int n = 0; n < 784; ++n) s += base[(size_t)n * 256 + t];
  if (t < 200) outp[b * 200 + t] = 1.f / (1.f + expf(-s * (1.f / 784.f)));

  if (DO_ATTEN) {
    __shared__ float labf[256];
    __shared__ float red[16];
    labf[t] = (t < 200) ? (float)label[b * 200 + t] : 0.f;
    __syncthreads();
    float att[4];
    float mn = 1e30f, mx = -1e30f;
#pragma unroll
    for (int i = 0; i < 4; ++i) {
      int n = t + i * 256;
      float a = 0.f;
      if (n < 784) {
        const float* rowp = base + (size_t)n * 256;
#pragma unroll 8
        for (int c = 0; c < 200; ++c) a += labf[c] * rowp[c];
        mn = fminf(mn, a);
        mx = fmaxf(mx, a);
      }
      att[i] = a;
    }
    for (int off = 32; off; off >>= 1) {
      mn = fminf(mn, __shfl_down(mn, off, 64));
      mx = fmaxf(mx, __shfl_down(mx, off, 64));
    }
    if ((t & 63) == 0) { red[(t >> 6) * 2] = mn; red[(t >> 6) * 2 + 1] = mx; }
    __syncthreads();
    if (t == 0) {
      float a = red[0], c = red[1];
      for (int wv = 1; wv < 4; ++wv) {
        a = fminf(a, red[wv * 2]);
        c = fmaxf(c, red[wv * 2 + 1]);
      }
      red[0] = a; red[1] = c;
    }
    __syncthreads();
    float gmn = red[0];
    float inv = 1.f / (red[1] - gmn);
#pragma unroll
    for (int i = 0; i < 4; ++i) {
      int n = t + i * 256;
      if (n < 784)
        mask[b * 784 + n] = ((att[i] - gmn) * inv >= 0.6f) ? 0.f : 1.f;
    }
  }
}

// ------------------- erase: featp interior *= mask (in place) ---------------
__global__ void erase_k(unsigned short* __restrict__ fp, const float* __restrict__ mask) {
  int i = blockIdx.x * 256 + threadIdx.x;
  if (i >= 32 * 28 * 28 * 512) return;
  int c = i & 511;
  int r2 = i >> 9;
  int xcol = r2 % 28;
  int r3 = r2 / 28;
  int y = r3 % 28;
  int b = r3 / 28;
  if (mask[b * 784 + y * 28 + xcol] == 0.f)
    fp[((size_t)(b * 30 + y + 1) * 32 + (xcol + 1)) * 512 + c] = 0;
}

// ---------------------------------------------------------------------------
extern "C" void kernel_launch(void* const* d_in, const int* in_sizes, int n_in,
                              void* d_out, int out_size, void* d_ws, size_t ws_size,
                              hipStream_t stream) {
  const float* x   = (const float*)d_in[0];
  const int* label = (const int*)d_in[1];
  const float* w1  = (const float*)d_in[2];
  const float* b1  = (const float*)d_in[3];
  const float* w2  = (const float*)d_in[4];
  const float* b2  = (const float*)d_in[5];
  const float* w3  = (const float*)d_in[6];
  const float* b3  = (const float*)d_in[7];
  const float* we1 = (const float*)d_in[8];
  const float* be1 = (const float*)d_in[9];
  const float* we2 = (const float*)d_in[10];
  const float* be2 = (const float*)d_in[11];
  const float* we3 = (const float*)d_in[12];
  const float* be3 = (const float*)d_in[13];
  float* outv = (float*)d_out;

  char* wp = (char*)d_ws;
  unsigned short* featp = (unsigned short*)wp; wp += 31457280;   // [32][30][32][512] bf16
  unsigned short* h1p   = (unsigned short*)wp; wp += 62914560;   // [32][30][32][1024] bf16
  unsigned short* h2p   = (unsigned short*)wp; wp += 62914560;
  unsigned short* Wt1   = (unsigned short*)wp; wp += 9437184;    // 9*1024*512
  unsigned short* Wt2   = (unsigned short*)wp; wp += 18874368;   // 9*1024*1024
  unsigned short* Wt3   = (unsigned short*)wp; wp += 524288;     // 256*1024
  float* outbuf         = (float*)wp;          wp += 25690112;   // [32][784][256] f32
  float* maskb          = (float*)wp;          wp += 100352;     // [32][784]

  zero_borders<<<5632, 256, 0, stream>>>(h1p, h2p, 1024);
  avgpool_k<<<dim3(32, 30, 4), 256, 0, stream>>>(x, featp);
  wprep3<<<(9 * 1024 * 512 + 255) / 256, 256, 0, stream>>>(w1, Wt1, 1024, 512);
  wprep3<<<(9 * 1024 * 1024 + 255) / 256, 256, 0, stream>>>(w2, Wt2, 1024, 1024);
  wprep1<<<(256 * 1024 + 255) / 256, 256, 0, stream>>>(w3, Wt3, 200, 256, 1024);

  // head 1
  conv_mfma<9, 1, 1><<<dim3(8, 7, 16), 256, 0, stream>>>(featp, Wt1, b1, h1p, 512, 1024, 1024);
  conv_mfma<9, 1, 1><<<dim3(8, 7, 16), 256, 0, stream>>>(h1p, Wt2, b2, h2p, 1024, 1024, 1024);
  conv_mfma<1, 0, 0><<<dim3(2, 7, 16), 256, 0, stream>>>(h2p, Wt3, b3, outbuf, 1024, 256, 200);
  logits_atten<1><<<32, 256, 0, stream>>>(outbuf, label, outv, maskb);

  // erase + head 2
  erase_k<<<(32 * 28 * 28 * 512 + 255) / 256, 256, 0, stream>>>(featp, maskb);
  wprep3<<<(9 * 1024 * 512 + 255) / 256, 256, 0, stream>>>(we1, Wt1, 1024, 512);
  wprep3<<<(9 * 1024 * 1024 + 255) / 256, 256, 0, stream>>>(we2, Wt2, 1024, 1024);
  wprep1<<<(256 * 1024 + 255) / 256, 256, 0, stream>>>(we3, Wt3, 200, 256, 1024);
  conv_mfma<9, 1, 1><<<dim3(8, 7, 16), 256, 0, stream>>>(featp, Wt1, be1, h1p, 512, 1024, 1024);
  conv_mfma<9, 1, 1><<<dim3(8, 7, 16), 256, 0, stream>>>(h1p, Wt2, be2, h2p, 1024, 1024, 1024);
  conv_mfma<1, 0, 0><<<dim3(2, 7, 16), 256, 0, stream>>>(h2p, Wt3, be3, outbuf, 1024, 256, 200);
  logits_atten<0><<<32, 256, 0, stream>>>(outbuf, nullptr, outv + 6400, nullptr);
}

// Round 3
// 5844.873 us; speedup vs baseline: 1.0091x; 1.0091x over previous
//
#include <hip/hip_runtime.h>
#include <hip/hip_bf16.h>
#include <stdint.h>

// ---------------------------------------------------------------------------
// VGG attention-erase pipeline, bf16 MFMA implicit-im2col convs.
// Activations channels-last, spatially padded: [b][30][32][C] bf16.
// Weights in MFMA-coalesced layout [p][O/16][C/32][lane64][8] bf16: each
// B-fragment load is one contiguous 1KB wave fetch, and the x%8 block->XCD
// round-robin keeps each 128-outch weight slice L2-resident per XCD.
// Weight loads use a distance-2 rolling 3-buffer prefetch flattened across
// the K-chunk boundary, so every load has >=2 p-iters (~272 cyc) of MFMA
// cover. Activations double-buffered in LDS (one barrier per K-chunk),
// staged via global_load_lds(16B, aux=0) with an XOR swizzle
// (kq ^ ((rc>>1)&3)) giving 2-way-max bank aliasing (free per m136).
// NO nontemporal hints anywhere: R2 showed NT stores cost 16x write
// amplification and NT act loads defeat cross-block L2/IC reuse.
// ---------------------------------------------------------------------------

typedef __attribute__((ext_vector_type(8))) short short8;
typedef __attribute__((ext_vector_type(4))) float floatx4;

__device__ __forceinline__ unsigned short f2bf(float f) {
  union { float f; uint32_t u; } cv; cv.f = f;
  uint32_t u = cv.u;
  u += 0x7fffu + ((u >> 16) & 1u);   // round-to-nearest-even
  return (unsigned short)(u >> 16);
}

// --- weight prep: w[O][C][3][3] f32 -> wt[p][O/16][C/32][lane][8] bf16 ------
__global__ void wprep3(const float* __restrict__ w, unsigned short* __restrict__ wt,
                       int O, int C) {
  int i = blockIdx.x * 256 + threadIdx.x;
  if (i >= 9 * O * C) return;
  int j = i & 7;
  int lane = (i >> 3) & 63;
  int kt = (i >> 9) % (C >> 5);
  int rest = (i >> 9) / (C >> 5);
  int ot = rest % (O >> 4);
  int p = rest / (O >> 4);
  int ln = lane & 15, kq = lane >> 4;
  int o = ot * 16 + ln;
  int c = kt * 32 + kq * 8 + j;
  wt[i] = f2bf(w[(size_t)(o * C + c) * 9 + p]);
}

// --- weight prep 1x1: w[O][C] f32 -> wt[OP/16][C/32][lane][8] (zero pad) ----
__global__ void wprep1(const float* __restrict__ w, unsigned short* __restrict__ wt,
                       int O, int OP, int C) {
  int i = blockIdx.x * 256 + threadIdx.x;
  if (i >= OP * C) return;
  int j = i & 7;
  int lane = (i >> 3) & 63;
  int kt = (i >> 9) % (C >> 5);
  int ot = (i >> 9) / (C >> 5);
  int ln = lane & 15, kq = lane >> 4;
  int o = ot * 16 + ln;
  int c = kt * 32 + kq * 8 + j;
  wt[i] = (o < O) ? f2bf(w[(size_t)o * C + c]) : (unsigned short)0;
}

// ------ avgpool 3x3/9 (count_include_pad) + transpose to ch-last padded -----
// x: [32][512][28][28] f32  ->  fp: [32][30][32][512] bf16 (borders zero)
__global__ void avgpool_k(const float* __restrict__ x, unsigned short* __restrict__ fp) {
  const int C = 512;
  int b = blockIdx.x, r = blockIdx.y, cg = blockIdx.z;  // r: padded row 0..29
  int t = threadIdx.x;
  __shared__ float xs[3 * 128 * 29];
  if (r == 0 || r == 29) {
    for (int i = t; i < 32 * 128; i += 256) {
      int c = i & 127, col = i >> 7;
      fp[((size_t)(b * 30 + r) * 32 + col) * C + cg * 128 + c] = 0;
    }
    return;
  }
  for (int i = t; i < 3 * 128 * 28; i += 256) {
    int dy = i / 3584;
    int rem = i - dy * 3584;
    int c = rem / 28, fx = rem - c * 28;
    int fy = r - 2 + dy;
    float v = (fy >= 0 && fy < 28)
                  ? x[((size_t)(b * 512 + cg * 128 + c) * 28 + fy) * 28 + fx]
                  : 0.f;
    xs[(dy * 128 + c) * 29 + fx] = v;
  }
  __syncthreads();
  for (int i = t; i < 32 * 128; i += 256) {
    int c = i & 127, col = i >> 7;
    float v = 0.f;
    if (col >= 1 && col <= 28) {
      int fx0 = col - 1;
#pragma unroll
      for (int dy = 0; dy < 3; ++dy)
#pragma unroll
        for (int dx = 0; dx < 3; ++dx) {
          int fx = fx0 - 1 + dx;
          if (fx >= 0 && fx < 28) v += xs[(dy * 128 + c) * 29 + fx];
        }
      v *= (1.f / 9.f);
    }
    fp[((size_t)(b * 30 + r) * 32 + col) * C + cg * 128 + c] = f2bf(v);
  }
}

// ---------- zero the padded borders of h1p/h2p (ws is poisoned per call) ----
__global__ void zero_borders(unsigned short* __restrict__ h1,
                             unsigned short* __restrict__ h2, int Mch) {
  int i = blockIdx.x * 256 + threadIdx.x;
  int vch = Mch >> 3;
  int perbuf = 32 * 176 * vch;
  if (i >= 2 * perbuf) return;
  unsigned short* h = (i < perbuf) ? h1 : h2;
  int j = (i < perbuf) ? i : i - perbuf;
  int cv = j % vch;
  int rr = j / vch;
  int bidx = rr / 176, e = rr - bidx * 176;
  int row, col;
  if (e < 32)      { row = 0;  col = e; }
  else if (e < 64) { row = 29; col = e - 32; }
  else {
    int q = e - 64;
    row = 1 + (q >> 2);
    int k = q & 3;
    col = (k == 0) ? 0 : 28 + k;
  }
  size_t addr = ((size_t)(bidx * 30 + row) * 32 + col) * Mch + cv * 8;
  *(uint4*)&h[addr] = (uint4){0u, 0u, 0u, 0u};
}

// ------------------------------- the conv GEMM ------------------------------
// fin: [B][30][32][C] bf16, wt: [P][M/16][C/32][64][8] bf16, bias: [OB] f32
// PADOUT=1: out bf16 [B][30][32][M] (interior only). PADOUT=0: out f32 [B][784][M].
template <int P, int RELU, int PADOUT>
__global__ __launch_bounds__(256, 2)
void conv_mfma(const unsigned short* __restrict__ fin,
               const unsigned short* __restrict__ wt,
               const float* __restrict__ bias,
               void* __restrict__ outp, int C, int M, int OB) {
  const int tid = threadIdx.x;
  const int lane = tid & 63;
  const int wave = tid >> 6;
  const int hB = wave & 1;      // batch half
  const int wo = wave >> 1;     // outch half
  const int ln = lane & 15;
  const int kq = lane >> 4;

  const int o0 = blockIdx.x * 128 + wo * 64;
  const int yo0 = blockIdx.y * 4;
  const int b0 = blockIdx.z * 2;
  const int bb = b0 + hB;

  __shared__ unsigned short ldsB[2 * 1536 * 8];  // 49152 B, double-buffered

  int baserc[7];
#pragma unroll
  for (int mi = 0; mi < 7; ++mi) {
    int n = mi * 16 + ln;
    int y = n / 28, x = n - y * 28;
    baserc[mi] = y * 32 + x;
  }

  floatx4 acc[7][4];
#pragma unroll
  for (int mi = 0; mi < 7; ++mi)
#pragma unroll
    for (int ni = 0; ni < 4; ++ni)
      acc[mi][ni] = (floatx4){0.f, 0.f, 0.f, 0.f};

  const size_t fin_b0 = (size_t)(b0 * 30 + yo0) * 32 * C;
  const size_t fin_b1 = (size_t)((b0 + 1) * 30 + yo0) * 32 * C;

  const int NC = C >> 5;
  const size_t wstep_n = (size_t)NC * 512;            // elements per o-tile
  const size_t wstep_p = (size_t)(M >> 4) * wstep_n;  // elements per p
  const unsigned short* wbase = wt + (size_t)(o0 >> 4) * wstep_n + lane * 8;

  auto stage = [&](int ckidx, int buf) {
    int ckoff = ckidx * 32;
#pragma unroll
    for (int it = 0; it < 6; ++it) {
      int wb = (it >= 3) ? 1 : 0;
      int u = (it - wb * 3) * 256 + tid;
      int rc = u >> 2;
      int cg = (u & 3) ^ ((rc >> 1) & 3);
      size_t goff = (wb ? fin_b1 : fin_b0) + (size_t)rc * C + ckoff + cg * 8;
      unsigned short* lp =
          &ldsB[(size_t)(buf * 1536 + wb * 768 + (it - wb * 3) * 256 + wave * 64) * 8];
      __builtin_amdgcn_global_load_lds((const uint32_t*)(fin + goff), (uint32_t*)lp,
                                       16, 0, 0);
    }
  };

  stage(0, 0);

  if (P == 9) {
    // rolling 3-buffer weight queue, prefetch distance 2 flattened over (ck,p);
    // phase stays aligned across chunks since 9 % 3 == 0.
    short8 wq[3][4];
#pragma unroll
    for (int ni = 0; ni < 4; ++ni) {
      wq[0][ni] = *(const short8*)(const void*)(wbase + ni * wstep_n);
      wq[1][ni] = *(const short8*)(const void*)(wbase + wstep_p + ni * wstep_n);
    }
    for (int ck = 0; ck < NC; ++ck) {
      __syncthreads();                 // drains stage(ck)
      if (ck + 1 < NC) stage(ck + 1, (ck + 1) & 1);
      const unsigned short* ldsH = &ldsB[(size_t)((ck & 1) * 1536 + hB * 768) * 8];
      const unsigned short* wck = wbase + (size_t)ck * 512;

#pragma unroll
      for (int p = 0; p < 9; ++p) {
        // prefetch (ck, p+2), rolling into (ck+1, p-7)
        const int pi = p + 2;
        if (pi < 9) {
#pragma unroll
          for (int ni = 0; ni < 4; ++ni)
            wq[pi % 3][ni] = *(const short8*)(const void*)(
                wck + (size_t)pi * wstep_p + ni * wstep_n);
        } else if (ck + 1 < NC) {
#pragma unroll
          for (int ni = 0; ni < 4; ++ni)
            wq[pi % 3][ni] = *(const short8*)(const void*)(
                wck + 512 + (size_t)(pi - 9) * wstep_p + ni * wstep_n);
        }
        const int dy = p / 3, dx = p - dy * 3;
        short8 af[7];
#pragma unroll
        for (int mi = 0; mi < 7; ++mi) {
          int rc = baserc[mi] + dy * 32 + dx;
          int u = (rc << 2) + (kq ^ ((rc >> 1) & 3));
          af[mi] = *(const short8*)(const void*)&ldsH[(unsigned)u * 8];
        }
#pragma unroll
        for (int mi = 0; mi < 7; ++mi)
#pragma unroll
          for (int ni = 0; ni < 4; ++ni)
            acc[mi][ni] = __builtin_amdgcn_mfma_f32_16x16x32_bf16(
                af[mi], wq[p % 3][ni], acc[mi][ni], 0, 0, 0);
      }
    }
  } else {
    // P == 1: two-buffer, prefetch next chunk's weights
    short8 wfA[4], wfB[4];
#pragma unroll
    for (int ni = 0; ni < 4; ++ni)
      wfA[ni] = *(const short8*)(const void*)(wbase + ni * wstep_n);
    for (int ck = 0; ck < NC; ++ck) {
      __syncthreads();
      if (ck + 1 < NC) {
        stage(ck + 1, (ck + 1) & 1);
#pragma unroll
        for (int ni = 0; ni < 4; ++ni)
          wfB[ni] = *(const short8*)(const void*)(wbase + (size_t)(ck + 1) * 512 +
                                                  ni * wstep_n);
      }
      const unsigned short* ldsH = &ldsB[(size_t)((ck & 1) * 1536 + hB * 768) * 8];
      short8 af[7];
#pragma unroll
      for (int mi = 0; mi < 7; ++mi) {
        int rc = baserc[mi] + 32 + 1;  // dy=1, dx=1
        rc = baserc[mi] + 33;
        int u = (rc << 2) + (kq ^ ((rc >> 1) & 3));
        af[mi] = *(const short8*)(const void*)&ldsH[(unsigned)u * 8];
      }
#pragma unroll
      for (int mi = 0; mi < 7; ++mi)
#pragma unroll
        for (int ni = 0; ni < 4; ++ni)
          acc[mi][ni] = __builtin_amdgcn_mfma_f32_16x16x32_bf16(af[mi], wfA[ni],
                                                                acc[mi][ni], 0, 0, 0);
#pragma unroll
      for (int ni = 0; ni < 4; ++ni) wfA[ni] = wfB[ni];
    }
  }

  // epilogue: D[row=spatial=(kq*4+j within 16-tile)][col=outch=ln]
  float bia[4];
#pragma unroll
  for (int ni = 0; ni < 4; ++ni) {
    int o = o0 + ni * 16 + ln;
    bia[ni] = (o < OB) ? bias[o] : 0.f;
  }
#pragma unroll
  for (int mi = 0; mi < 7; ++mi) {
#pragma unroll
    for (int j = 0; j < 4; ++j) {
      int n = mi * 16 + kq * 4 + j;
      int y = n / 28, x = n - y * 28;
#pragma unroll
      for (int ni = 0; ni < 4; ++ni) {
        int o = o0 + ni * 16 + ln;
        float v = acc[mi][ni][j] + bia[ni];
        if (RELU) v = fmaxf(v, 0.f);
        if (PADOUT) {
          size_t addr = ((size_t)(bb * 30 + yo0 + y + 1) * 32 + (x + 1)) * M + o;
          ((unsigned short*)outp)[addr] = f2bf(v);
        } else {
          size_t addr = ((size_t)bb * 784 + (yo0 + y) * 28 + x) * M + o;
          ((float*)outp)[addr] = v;
        }
      }
    }
  }
}

// ------------- logits (+ optional attention/mask), one block per batch ------
template <int DO_ATTEN>
__global__ void logits_atten(const float* __restrict__ ob, const int* __restrict__ label,
                             float* __restrict__ outp, float* __restrict__ mask) {
  int b = blockIdx.x, t = threadIdx.x;
  const float* base = ob + (size_t)b * 784 * 256;
  float s = 0.f;
#pragma unroll 16
  for (int n = 0; n < 784; ++n) s += base[(size_t)n * 256 + t];
  if (t < 200) outp[b * 200 + t] = 1.f / (1.f + expf(-s * (1.f / 784.f)));

  if (DO_ATTEN) {
    __shared__ float labf[256];
    __shared__ float red[16];
    labf[t] = (t < 200) ? (float)label[b * 200 + t] : 0.f;
    __syncthreads();
    float att[4];
    float mn = 1e30f, mx = -1e30f;
#pragma unroll
    for (int i = 0; i < 4; ++i) {
      int n = t + i * 256;
      float a = 0.f;
      if (n < 784) {
        const float* rowp = base + (size_t)n * 256;
#pragma unroll 8
        for (int c = 0; c < 200; ++c) a += labf[c] * rowp[c];
        mn = fminf(mn, a);
        mx = fmaxf(mx, a);
      }
      att[i] = a;
    }
    for (int off = 32; off; off >>= 1) {
      mn = fminf(mn, __shfl_down(mn, off, 64));
      mx = fmaxf(mx, __shfl_down(mx, off, 64));
    }
    if ((t & 63) == 0) { red[(t >> 6) * 2] = mn; red[(t >> 6) * 2 + 1] = mx; }
    __syncthreads();
    if (t == 0) {
      float a = red[0], c = red[1];
      for (int wv = 1; wv < 4; ++wv) {
        a = fminf(a, red[wv * 2]);
        c = fmaxf(c, red[wv * 2 + 1]);
      }
      red[0] = a; red[1] = c;
    }
    __syncthreads();
    float gmn = red[0];
    float inv = 1.f / (red[1] - gmn);
#pragma unroll
    for (int i = 0; i < 4; ++i) {
      int n = t + i * 256;
      if (n < 784)
        mask[b * 784 + n] = ((att[i] - gmn) * inv >= 0.6f) ? 0.f : 1.f;
    }
  }
}

// ------------------- erase: featp interior *= mask (in place) ---------------
__global__ void erase_k(unsigned short* __restrict__ fp, const float* __restrict__ mask) {
  int i = blockIdx.x * 256 + threadIdx.x;
  if (i >= 32 * 28 * 28 * 512) return;
  int c = i & 511;
  int r2 = i >> 9;
  int xcol = r2 % 28;
  int r3 = r2 / 28;
  int y = r3 % 28;
  int b = r3 / 28;
  if (mask[b * 784 + y * 28 + xcol] == 0.f)
    fp[((size_t)(b * 30 + y + 1) * 32 + (xcol + 1)) * 512 + c] = 0;
}

// ---------------------------------------------------------------------------
extern "C" void kernel_launch(void* const* d_in, const int* in_sizes, int n_in,
                              void* d_out, int out_size, void* d_ws, size_t ws_size,
                              hipStream_t stream) {
  const float* x   = (const float*)d_in[0];
  const int* label = (const int*)d_in[1];
  const float* w1  = (const float*)d_in[2];
  const float* b1  = (const float*)d_in[3];
  const float* w2  = (const float*)d_in[4];
  const float* b2  = (const float*)d_in[5];
  const float* w3  = (const float*)d_in[6];
  const float* b3  = (const float*)d_in[7];
  const float* we1 = (const float*)d_in[8];
  const float* be1 = (const float*)d_in[9];
  const float* we2 = (const float*)d_in[10];
  const float* be2 = (const float*)d_in[11];
  const float* we3 = (const float*)d_in[12];
  const float* be3 = (const float*)d_in[13];
  float* outv = (float*)d_out;

  char* wp = (char*)d_ws;
  unsigned short* featp = (unsigned short*)wp; wp += 31457280;   // [32][30][32][512] bf16
  unsigned short* h1p   = (unsigned short*)wp; wp += 62914560;   // [32][30][32][1024] bf16
  unsigned short* h2p   = (unsigned short*)wp; wp += 62914560;
  unsigned short* Wt1   = (unsigned short*)wp; wp += 9437184;    // 9*1024*512
  unsigned short* Wt2   = (unsigned short*)wp; wp += 18874368;   // 9*1024*1024
  unsigned short* Wt3   = (unsigned short*)wp; wp += 524288;     // 256*1024
  float* outbuf         = (float*)wp;          wp += 25690112;   // [32][784][256] f32
  float* maskb          = (float*)wp;          wp += 100352;     // [32][784]

  zero_borders<<<5632, 256, 0, stream>>>(h1p, h2p, 1024);
  avgpool_k<<<dim3(32, 30, 4), 256, 0, stream>>>(x, featp);
  wprep3<<<(9 * 1024 * 512 + 255) / 256, 256, 0, stream>>>(w1, Wt1, 1024, 512);
  wprep3<<<(9 * 1024 * 1024 + 255) / 256, 256, 0, stream>>>(w2, Wt2, 1024, 1024);
  wprep1<<<(256 * 1024 + 255) / 256, 256, 0, stream>>>(w3, Wt3, 200, 256, 1024);

  // head 1
  conv_mfma<9, 1, 1><<<dim3(8, 7, 16), 256, 0, stream>>>(featp, Wt1, b1, h1p, 512, 1024, 1024);
  conv_mfma<9, 1, 1><<<dim3(8, 7, 16), 256, 0, stream>>>(h1p, Wt2, b2, h2p, 1024, 1024, 1024);
  conv_mfma<1, 0, 0><<<dim3(2, 7, 16), 256, 0, stream>>>(h2p, Wt3, b3, outbuf, 1024, 256, 200);
  logits_atten<1><<<32, 256, 0, stream>>>(outbuf, label, outv, maskb);

  // erase + head 2
  erase_k<<<(32 * 28 * 28 * 512 + 255) / 256, 256, 0, stream>>>(featp, maskb);
  wprep3<<<(9 * 1024 * 512 + 255) / 256, 256, 0, stream>>>(we1, Wt1, 1024, 512);
  wprep3<<<(9 * 1024 * 1024 + 255) / 256, 256, 0, stream>>>(we2, Wt2, 1024, 1024);
  wprep1<<<(256 * 1024 + 255) / 256, 256, 0, stream>>>(we3, Wt3, 200, 256, 1024);
  conv_mfma<9, 1, 1><<<dim3(8, 7, 16), 256, 0, stream>>>(featp, Wt1, be1, h1p, 512, 1024, 1024);
  conv_mfma<9, 1, 1><<<dim3(8, 7, 16), 256, 0, stream>>>(h1p, Wt2, be2, h2p, 1024, 1024, 1024);
  conv_mfma<1, 0, 0><<<dim3(2, 7, 16), 256, 0, stream>>>(h2p, Wt3, be3, outbuf, 1024, 256, 200);
  logits_atten<0><<<32, 256, 0, stream>>>(outbuf, nullptr, outv + 6400, nullptr);
}

// Round 4
// 5423.227 us; speedup vs baseline: 1.0875x; 1.0777x over previous
//
#include <hip/hip_runtime.h>
#include <hip/hip_bf16.h>
#include <stdint.h>

// ---------------------------------------------------------------------------
// VGG attention-erase pipeline, bf16 MFMA implicit-im2col convs.
// Activations channels-last, spatially padded: [b][30][32][C] bf16.
// Weights in MFMA-coalesced layout [p][O/16][C/32][lane64][8] bf16 (each
// B-frag load = one contiguous 1KB wave fetch).
// Conv block: 512 threads = 8 waves = 4 batches x 2 outch-halves; each wave
// computes 112 spatial x 64 outch with 16x16x32 bf16 MFMA. 4 waves/block
// share identical weight fragments (L1 hits), and 4-batch blocks halve the
// weight request volume vs 2-batch (448 blocks x 2.3MB for conv2).
// Acts staged per 32-ch chunk into 48KB LDS (single buffer, m97-style
// 2-barrier loop) via global_load_lds(16B) with XOR swizzle
// (kq ^ ((rc>>1)&3)) -> <=2-way bank aliasing (free per m136).
// Weight prefetch: 2-buffer distance-1, copy-rotated (32 VGPRs total).
// REGISTER BUDGET IS THE CLIFF: unified VGPR+AGPR = 256/wave at 8 waves/CU.
// acc 112 (AGPR) + weights 32 + af 28 + misc ~60 = ~232. R2/R3's 3-buffer
// queue (+16 regs) spilled ~1.5GB/dispatch to scratch - do not re-add.
// ---------------------------------------------------------------------------

typedef __attribute__((ext_vector_type(8))) short short8;
typedef __attribute__((ext_vector_type(4))) float floatx4;

__device__ __forceinline__ unsigned short f2bf(float f) {
  union { float f; uint32_t u; } cv; cv.f = f;
  uint32_t u = cv.u;
  u += 0x7fffu + ((u >> 16) & 1u);   // round-to-nearest-even
  return (unsigned short)(u >> 16);
}

// --- weight prep: w[O][C][3][3] f32 -> wt[p][O/16][C/32][lane][8] bf16 ------
__global__ void wprep3(const float* __restrict__ w, unsigned short* __restrict__ wt,
                       int O, int C) {
  int i = blockIdx.x * 256 + threadIdx.x;
  if (i >= 9 * O * C) return;
  int j = i & 7;
  int lane = (i >> 3) & 63;
  int kt = (i >> 9) % (C >> 5);
  int rest = (i >> 9) / (C >> 5);
  int ot = rest % (O >> 4);
  int p = rest / (O >> 4);
  int ln = lane & 15, kq = lane >> 4;
  int o = ot * 16 + ln;
  int c = kt * 32 + kq * 8 + j;
  wt[i] = f2bf(w[(size_t)(o * C + c) * 9 + p]);
}

// --- weight prep 1x1: w[O][C] f32 -> wt[OP/16][C/32][lane][8] (zero pad) ----
__global__ void wprep1(const float* __restrict__ w, unsigned short* __restrict__ wt,
                       int O, int OP, int C) {
  int i = blockIdx.x * 256 + threadIdx.x;
  if (i >= OP * C) return;
  int j = i & 7;
  int lane = (i >> 3) & 63;
  int kt = (i >> 9) % (C >> 5);
  int ot = (i >> 9) / (C >> 5);
  int ln = lane & 15, kq = lane >> 4;
  int o = ot * 16 + ln;
  int c = kt * 32 + kq * 8 + j;
  wt[i] = (o < O) ? f2bf(w[(size_t)o * C + c]) : (unsigned short)0;
}

// ------ avgpool 3x3/9 (count_include_pad) + transpose to ch-last padded -----
// x: [32][512][28][28] f32  ->  fp: [32][30][32][512] bf16 (borders zero)
__global__ void avgpool_k(const float* __restrict__ x, unsigned short* __restrict__ fp) {
  const int C = 512;
  int b = blockIdx.x, r = blockIdx.y, cg = blockIdx.z;  // r: padded row 0..29
  int t = threadIdx.x;
  __shared__ float xs[3 * 128 * 29];
  if (r == 0 || r == 29) {
    for (int i = t; i < 32 * 128; i += 256) {
      int c = i & 127, col = i >> 7;
      fp[((size_t)(b * 30 + r) * 32 + col) * C + cg * 128 + c] = 0;
    }
    return;
  }
  for (int i = t; i < 3 * 128 * 28; i += 256) {
    int dy = i / 3584;
    int rem = i - dy * 3584;
    int c = rem / 28, fx = rem - c * 28;
    int fy = r - 2 + dy;
    float v = (fy >= 0 && fy < 28)
                  ? x[((size_t)(b * 512 + cg * 128 + c) * 28 + fy) * 28 + fx]
                  : 0.f;
    xs[(dy * 128 + c) * 29 + fx] = v;
  }
  __syncthreads();
  for (int i = t; i < 32 * 128; i += 256) {
    int c = i & 127, col = i >> 7;
    float v = 0.f;
    if (col >= 1 && col <= 28) {
      int fx0 = col - 1;
#pragma unroll
      for (int dy = 0; dy < 3; ++dy)
#pragma unroll
        for (int dx = 0; dx < 3; ++dx) {
          int fx = fx0 - 1 + dx;
          if (fx >= 0 && fx < 28) v += xs[(dy * 128 + c) * 29 + fx];
        }
      v *= (1.f / 9.f);
    }
    fp[((size_t)(b * 30 + r) * 32 + col) * C + cg * 128 + c] = f2bf(v);
  }
}

// ---------- zero the padded borders of h1p/h2p (ws is poisoned per call) ----
__global__ void zero_borders(unsigned short* __restrict__ h1,
                             unsigned short* __restrict__ h2, int Mch) {
  int i = blockIdx.x * 256 + threadIdx.x;
  int vch = Mch >> 3;
  int perbuf = 32 * 176 * vch;
  if (i >= 2 * perbuf) return;
  unsigned short* h = (i < perbuf) ? h1 : h2;
  int j = (i < perbuf) ? i : i - perbuf;
  int cv = j % vch;
  int rr = j / vch;
  int bidx = rr / 176, e = rr - bidx * 176;
  int row, col;
  if (e < 32)      { row = 0;  col = e; }
  else if (e < 64) { row = 29; col = e - 32; }
  else {
    int q = e - 64;
    row = 1 + (q >> 2);
    int k = q & 3;
    col = (k == 0) ? 0 : 28 + k;
  }
  size_t addr = ((size_t)(bidx * 30 + row) * 32 + col) * Mch + cv * 8;
  *(uint4*)&h[addr] = (uint4){0u, 0u, 0u, 0u};
}

// ------------------------------- the conv GEMM ------------------------------
// fin: [B][30][32][C] bf16, wt: [P][M/16][C/32][64][8] bf16, bias: [OB] f32
// PADOUT=1: out bf16 [B][30][32][M] (interior only). PADOUT=0: out f32 [B][784][M].
// grid: (M/128, 7, 8), block 512.
template <int P, int RELU, int PADOUT>
__global__ __launch_bounds__(512, 2)
void conv_mfma(const unsigned short* __restrict__ fin,
               const unsigned short* __restrict__ wt,
               const float* __restrict__ bias,
               void* __restrict__ outp, int C, int M, int OB) {
  const int tid = threadIdx.x;
  const int lane = tid & 63;
  const int wave = tid >> 6;   // 0..7
  const int hB = wave & 3;     // batch within block
  const int wo = wave >> 2;    // outch half
  const int ln = lane & 15;
  const int kq = lane >> 4;

  const int o0 = blockIdx.x * 128 + wo * 64;
  const int yo0 = blockIdx.y * 4;
  const int b0 = blockIdx.z * 4;
  const int bb = b0 + hB;

  __shared__ unsigned short ldsB[3072 * 8];  // 48 KB: 4 batches x 768 16B-units

  int baserc[7];
#pragma unroll
  for (int mi = 0; mi < 7; ++mi) {
    int n = mi * 16 + ln;
    int y = n / 28, x = n - y * 28;
    baserc[mi] = y * 32 + x;
  }

  floatx4 acc[7][4];
#pragma unroll
  for (int mi = 0; mi < 7; ++mi)
#pragma unroll
    for (int ni = 0; ni < 4; ++ni)
      acc[mi][ni] = (floatx4){0.f, 0.f, 0.f, 0.f};

  size_t fin_b[4];
#pragma unroll
  for (int q = 0; q < 4; ++q)
    fin_b[q] = (size_t)((b0 + q) * 30 + yo0) * 32 * C;

  const int NC = C >> 5;
  const size_t wstep_n = (size_t)NC * 512;            // elements per o-tile
  const size_t wstep_p = (size_t)(M >> 4) * wstep_n;  // elements per p
  const unsigned short* wbase = wt + (size_t)(o0 >> 4) * wstep_n + lane * 8;

  auto stage = [&](int ckidx) {
    int ckoff = ckidx * 32;
#pragma unroll
    for (int it = 0; it < 6; ++it) {
      int u = it * 512 + tid;                 // 0..3071; wave never straddles 768
      int wb = (u >= 2304) ? 3 : (u >= 1536) ? 2 : (u >= 768) ? 1 : 0;
      int ub = u - wb * 768;
      int rc = ub >> 2;
      int cg = (ub & 3) ^ ((rc >> 1) & 3);
      size_t goff = fin_b[wb] + (size_t)rc * C + ckoff + cg * 8;
      unsigned short* lp = &ldsB[(size_t)u * 8];
      __builtin_amdgcn_global_load_lds((const uint32_t*)(fin + goff), (uint32_t*)lp,
                                       16, 0, 0);
    }
  };

  const unsigned short* ldsH = &ldsB[(size_t)(hB * 768) * 8];

  // 2-buffer distance-1 weight prefetch, copy-rotated (32 regs sustained).
  short8 wfA[4], wfB[4];
#pragma unroll
  for (int ni = 0; ni < 4; ++ni)
    wfA[ni] = *(const short8*)(const void*)(wbase + ni * wstep_n);

  for (int ck = 0; ck < NC; ++ck) {
    __syncthreads();                 // prev chunk's readers done
    stage(ck);
    __syncthreads();                 // staging complete
    const unsigned short* wck = wbase + (size_t)ck * 512;

#pragma unroll
    for (int p = 0; p < P; ++p) {
      // prefetch next (ck,p+1) or (ck+1,0)
      if (p + 1 < P) {
#pragma unroll
        for (int ni = 0; ni < 4; ++ni)
          wfB[ni] = *(const short8*)(const void*)(
              wck + (size_t)(p + 1) * wstep_p + ni * wstep_n);
      } else if (ck + 1 < NC) {
#pragma unroll
        for (int ni = 0; ni < 4; ++ni)
          wfB[ni] = *(const short8*)(const void*)(wck + 512 + ni * wstep_n);
      }
      int dy, dx;
      if (P == 1) { dy = 1; dx = 1; } else { dy = p / 3; dx = p - dy * 3; }
      short8 af[7];
#pragma unroll
      for (int mi = 0; mi < 7; ++mi) {
        int rc = baserc[mi] + dy * 32 + dx;
        int u = (rc << 2) + (kq ^ ((rc >> 1) & 3));
        af[mi] = *(const short8*)(const void*)&ldsH[(unsigned)u * 8];
      }
#pragma unroll
      for (int mi = 0; mi < 7; ++mi)
#pragma unroll
        for (int ni = 0; ni < 4; ++ni)
          acc[mi][ni] = __builtin_amdgcn_mfma_f32_16x16x32_bf16(af[mi], wfA[ni],
                                                                acc[mi][ni], 0, 0, 0);
      // rotate (renamed away inside the unrolled body; real movs only at
      // the ck back-edge)
#pragma unroll
      for (int ni = 0; ni < 4; ++ni) wfA[ni] = wfB[ni];
    }
  }

  // epilogue: D[row=spatial=(kq*4+j within 16-tile)][col=outch=ln]
  float bia[4];
#pragma unroll
  for (int ni = 0; ni < 4; ++ni) {
    int o = o0 + ni * 16 + ln;
    bia[ni] = (o < OB) ? bias[o] : 0.f;
  }
#pragma unroll
  for (int mi = 0; mi < 7; ++mi) {
#pragma unroll
    for (int j = 0; j < 4; ++j) {
      int n = mi * 16 + kq * 4 + j;
      int y = n / 28, x = n - y * 28;
#pragma unroll
      for (int ni = 0; ni < 4; ++ni) {
        int o = o0 + ni * 16 + ln;
        float v = acc[mi][ni][j] + bia[ni];
        if (RELU) v = fmaxf(v, 0.f);
        if (PADOUT) {
          size_t addr = ((size_t)(bb * 30 + yo0 + y + 1) * 32 + (x + 1)) * M + o;
          ((unsigned short*)outp)[addr] = f2bf(v);
        } else {
          size_t addr = ((size_t)bb * 784 + (yo0 + y) * 28 + x) * M + o;
          ((float*)outp)[addr] = v;
        }
      }
    }
  }
}

// ------------- logits (+ optional attention/mask), one block per batch ------
template <int DO_ATTEN>
__global__ void logits_atten(const float* __restrict__ ob, const int* __restrict__ label,
                             float* __restrict__ outp, float* __restrict__ mask) {
  int b = blockIdx.x, t = threadIdx.x;
  const float* base = ob + (size_t)b * 784 * 256;
  float s = 0.f;
#pragma unroll 16
  for (int n = 0; n < 784; ++n) s += base[(size_t)n * 256 + t];
  if (t < 200) outp[b * 200 + t] = 1.f / (1.f + expf(-s * (1.f / 784.f)));

  if (DO_ATTEN) {
    __shared__ float labf[256];
    __shared__ float red[16];
    labf[t] = (t < 200) ? (float)label[b * 200 + t] : 0.f;
    __syncthreads();
    float att[4];
    float mn = 1e30f, mx = -1e30f;
#pragma unroll
    for (int i = 0; i < 4; ++i) {
      int n = t + i * 256;
      float a = 0.f;
      if (n < 784) {
        const float* rowp = base + (size_t)n * 256;
#pragma unroll 8
        for (int c = 0; c < 200; ++c) a += labf[c] * rowp[c];
        mn = fminf(mn, a);
        mx = fmaxf(mx, a);
      }
      att[i] = a;
    }
    for (int off = 32; off; off >>= 1) {
      mn = fminf(mn, __shfl_down(mn, off, 64));
      mx = fmaxf(mx, __shfl_down(mx, off, 64));
    }
    if ((t & 63) == 0) { red[(t >> 6) * 2] = mn; red[(t >> 6) * 2 + 1] = mx; }
    __syncthreads();
    if (t == 0) {
      float a = red[0], c = red[1];
      for (int wv = 1; wv < 4; ++wv) {
        a = fminf(a, red[wv * 2]);
        c = fmaxf(c, red[wv * 2 + 1]);
      }
      red[0] = a; red[1] = c;
    }
    __syncthreads();
    float gmn = red[0];
    float inv = 1.f / (red[1] - gmn);
#pragma unroll
    for (int i = 0; i < 4; ++i) {
      int n = t + i * 256;
      if (n < 784)
        mask[b * 784 + n] = ((att[i] - gmn) * inv >= 0.6f) ? 0.f : 1.f;
    }
  }
}

// ------------------- erase: featp interior *= mask (in place) ---------------
__global__ void erase_k(unsigned short* __restrict__ fp, const float* __restrict__ mask) {
  int i = blockIdx.x * 256 + threadIdx.x;
  if (i >= 32 * 28 * 28 * 512) return;
  int c = i & 511;
  int r2 = i >> 9;
  int xcol = r2 % 28;
  int r3 = r2 / 28;
  int y = r3 % 28;
  int b = r3 / 28;
  if (mask[b * 784 + y * 28 + xcol] == 0.f)
    fp[((size_t)(b * 30 + y + 1) * 32 + (xcol + 1)) * 512 + c] = 0;
}

// ---------------------------------------------------------------------------
extern "C" void kernel_launch(void* const* d_in, const int* in_sizes, int n_in,
                              void* d_out, int out_size, void* d_ws, size_t ws_size,
                              hipStream_t stream) {
  const float* x   = (const float*)d_in[0];
  const int* label = (const int*)d_in[1];
  const float* w1  = (const float*)d_in[2];
  const float* b1  = (const float*)d_in[3];
  const float* w2  = (const float*)d_in[4];
  const float* b2  = (const float*)d_in[5];
  const float* w3  = (const float*)d_in[6];
  const float* b3  = (const float*)d_in[7];
  const float* we1 = (const float*)d_in[8];
  const float* be1 = (const float*)d_in[9];
  const float* we2 = (const float*)d_in[10];
  const float* be2 = (const float*)d_in[11];
  const float* we3 = (const float*)d_in[12];
  const float* be3 = (const float*)d_in[13];
  float* outv = (float*)d_out;

  char* wp = (char*)d_ws;
  unsigned short* featp = (unsigned short*)wp; wp += 31457280;   // [32][30][32][512] bf16
  unsigned short* h1p   = (unsigned short*)wp; wp += 62914560;   // [32][30][32][1024] bf16
  unsigned short* h2p   = (unsigned short*)wp; wp += 62914560;
  unsigned short* Wt1   = (unsigned short*)wp; wp += 9437184;    // 9*1024*512
  unsigned short* Wt2   = (unsigned short*)wp; wp += 18874368;   // 9*1024*1024
  unsigned short* Wt3   = (unsigned short*)wp; wp += 524288;     // 256*1024
  float* outbuf         = (float*)wp;          wp += 25690112;   // [32][784][256] f32
  float* maskb          = (float*)wp;          wp += 100352;     // [32][784]

  zero_borders<<<5632, 256, 0, stream>>>(h1p, h2p, 1024);
  avgpool_k<<<dim3(32, 30, 4), 256, 0, stream>>>(x, featp);
  wprep3<<<(9 * 1024 * 512 + 255) / 256, 256, 0, stream>>>(w1, Wt1, 1024, 512);
  wprep3<<<(9 * 1024 * 1024 + 255) / 256, 256, 0, stream>>>(w2, Wt2, 1024, 1024);
  wprep1<<<(256 * 1024 + 255) / 256, 256, 0, stream>>>(w3, Wt3, 200, 256, 1024);

  // head 1
  conv_mfma<9, 1, 1><<<dim3(8, 7, 8), 512, 0, stream>>>(featp, Wt1, b1, h1p, 512, 1024, 1024);
  conv_mfma<9, 1, 1><<<dim3(8, 7, 8), 512, 0, stream>>>(h1p, Wt2, b2, h2p, 1024, 1024, 1024);
  conv_mfma<1, 0, 0><<<dim3(2, 7, 8), 512, 0, stream>>>(h2p, Wt3, b3, outbuf, 1024, 256, 200);
  logits_atten<1><<<32, 256, 0, stream>>>(outbuf, label, outv, maskb);

  // erase + head 2
  erase_k<<<(32 * 28 * 28 * 512 + 255) / 256, 256, 0, stream>>>(featp, maskb);
  wprep3<<<(9 * 1024 * 512 + 255) / 256, 256, 0, stream>>>(we1, Wt1, 1024, 512);
  wprep3<<<(9 * 1024 * 1024 + 255) / 256, 256, 0, stream>>>(we2, Wt2, 1024, 1024);
  wprep1<<<(256 * 1024 + 255) / 256, 256, 0, stream>>>(we3, Wt3, 200, 256, 1024);
  conv_mfma<9, 1, 1><<<dim3(8, 7, 8), 512, 0, stream>>>(featp, Wt1, be1, h1p, 512, 1024, 1024);
  conv_mfma<9, 1, 1><<<dim3(8, 7, 8), 512, 0, stream>>>(h1p, Wt2, be2, h2p, 1024, 1024, 1024);
  conv_mfma<1, 0, 0><<<dim3(2, 7, 8), 512, 0, stream>>>(h2p, Wt3, be3, outbuf, 1024, 256, 200);
  logits_atten<0><<<32, 256, 0, stream>>>(outbuf, nullptr, outv + 6400, nullptr);
}